// Round 3
// baseline (1582.733 us; speedup 1.0000x reference)
//
#include <hip/hip_runtime.h>
#include <hip/hip_bf16.h>

typedef __bf16 bf16_t;
typedef __bf16 bf16x8 __attribute__((ext_vector_type(8)));
typedef float f32x4 __attribute__((ext_vector_type(4)));

#define B_    4
#define LQ_   13343
#define D_    256
#define H_    8
#define HD_   32
#define DFF_  2048
#define M_    (B_ * LQ_)   // 53372 tokens

// ---------------- GEMM: C = A[M,K] @ Bt[N,K]^T + bias ----------------
// A is f32 (AF32=true, converted to bf16 in regs) or bf16. Bt is bf16.
#define BM 128
#define BN 128
#define BK 32
#define LDSS 40   // 40 elems = 80 B stride (5×16 B, ds_*_b128-safe), breaks bank aliasing

#define MODE_F32       0
#define MODE_F32_ACC   1
#define MODE_BF16      2
#define MODE_BF16_RELU 3

template <int MODE, bool AF32>
__global__ __launch_bounds__(256) void gemm_bt(
    const void* __restrict__ Av, int lda,
    const bf16_t* __restrict__ Bt, int ldb,
    const float* __restrict__ bias,
    void* __restrict__ Cv, int ldc,
    int M, int N, int K)
{
  __shared__ alignas(16) bf16_t As[BM * LDSS];
  __shared__ alignas(16) bf16_t Bs[BN * LDSS];
  const int tid  = threadIdx.x;
  const int wave = tid >> 6, lane = tid & 63;
  const int m0 = blockIdx.x * BM;
  const int n0 = blockIdx.y * BN;
  const int wm = (wave & 1) * 64;
  const int wn = (wave >> 1) * 64;
  const int lrow = lane & 15;
  const int quad = lane >> 4;

  f32x4 acc[4][4] = {};

  const int r0 = tid >> 2;          // 0..63
  const int kc = (tid & 3) * 8;     // 0,8,16,24

  for (int kt = 0; kt < K; kt += BK) {
    bf16x8 a0 = {}, a1 = {}, b0 = {}, b1 = {};
    int gm0 = m0 + r0, gm1 = m0 + r0 + 64;
    if (AF32) {
      const float* Af = (const float*)Av;
      if (gm0 < M) {
        const float* p = Af + (size_t)gm0 * lda + kt + kc;
#pragma unroll
        for (int j = 0; j < 8; ++j) a0[j] = (bf16_t)p[j];
      }
      if (gm1 < M) {
        const float* p = Af + (size_t)gm1 * lda + kt + kc;
#pragma unroll
        for (int j = 0; j < 8; ++j) a1[j] = (bf16_t)p[j];
      }
    } else {
      const bf16_t* Ab = (const bf16_t*)Av;
      if (gm0 < M) a0 = *(const bf16x8*)(Ab + (size_t)gm0 * lda + kt + kc);
      if (gm1 < M) a1 = *(const bf16x8*)(Ab + (size_t)gm1 * lda + kt + kc);
    }
    int gn0 = n0 + r0, gn1 = n0 + r0 + 64;
    if (gn0 < N) b0 = *(const bf16x8*)(Bt + (size_t)gn0 * ldb + kt + kc);
    if (gn1 < N) b1 = *(const bf16x8*)(Bt + (size_t)gn1 * ldb + kt + kc);
    __syncthreads();  // previous iter's LDS reads complete
    *(bf16x8*)(&As[r0 * LDSS + kc])        = a0;
    *(bf16x8*)(&As[(r0 + 64) * LDSS + kc]) = a1;
    *(bf16x8*)(&Bs[r0 * LDSS + kc])        = b0;
    *(bf16x8*)(&Bs[(r0 + 64) * LDSS + kc]) = b1;
    __syncthreads();
    bf16x8 af[4], bfr[4];
#pragma unroll
    for (int i = 0; i < 4; ++i)
      af[i] = *(const bf16x8*)(&As[(wm + i * 16 + lrow) * LDSS + quad * 8]);
#pragma unroll
    for (int j = 0; j < 4; ++j)
      bfr[j] = *(const bf16x8*)(&Bs[(wn + j * 16 + lrow) * LDSS + quad * 8]);
#pragma unroll
    for (int i = 0; i < 4; ++i)
#pragma unroll
      for (int j = 0; j < 4; ++j)
        acc[i][j] = __builtin_amdgcn_mfma_f32_16x16x32_bf16(af[i], bfr[j], acc[i][j], 0, 0, 0);
  }

  float*  Cf = (float*)Cv;
  bf16_t* Cb = (bf16_t*)Cv;
#pragma unroll
  for (int i = 0; i < 4; ++i) {
#pragma unroll
    for (int j = 0; j < 4; ++j) {
      int gn = n0 + wn + j * 16 + lrow;
      if (gn >= N) continue;
      float bv = bias ? bias[gn] : 0.f;
#pragma unroll
      for (int r = 0; r < 4; ++r) {
        int gm = m0 + wm + i * 16 + quad * 4 + r;
        if (gm >= M) continue;
        float v = acc[i][j][r] + bv;
        size_t ci = (size_t)gm * ldc + gn;
        if (MODE == MODE_F32)          Cf[ci] = v;
        else if (MODE == MODE_F32_ACC) Cf[ci] += v;
        else if (MODE == MODE_BF16)    Cb[ci] = (bf16_t)v;
        else                           Cb[ci] = (bf16_t)(v > 0.f ? v : 0.f);
      }
    }
  }
}

// ---------------- small kernels ----------------
// out[n*K+k] = (bf16)in[k*N+n]  (f32 [K,N] -> bf16 [N,K])
__global__ void k_transpose(const float* __restrict__ in, bf16_t* __restrict__ out,
                            int K, int N) {
  int idx = blockIdx.x * 256 + threadIdx.x;
  if (idx >= K * N) return;
  int n = idx / K, k = idx - n * K;
  out[idx] = (bf16_t)in[(size_t)k * N + n];
}

// q = bf16(src + pos), 8 elems/thread
__global__ void k_addpos(const float* __restrict__ a, const float* __restrict__ b,
                         bf16_t* __restrict__ o, int n8) {
  int i = blockIdx.x * blockDim.x + threadIdx.x;
  if (i >= n8) return;
  bf16x8 z;
#pragma unroll
  for (int j = 0; j < 8; ++j) z[j] = (bf16_t)(a[i * 8 + j] + b[i * 8 + j]);
  ((bf16x8*)o)[i] = z;
}

__global__ void k_softmax20(float* __restrict__ a, int rows) {
  int r = blockIdx.x * blockDim.x + threadIdx.x;
  if (r >= rows) return;
  float* p = a + (size_t)r * 20;
  float mx = p[0];
#pragma unroll
  for (int i = 1; i < 20; ++i) mx = fmaxf(mx, p[i]);
  float e[20], s = 0.f;
#pragma unroll
  for (int i = 0; i < 20; ++i) { e[i] = expf(p[i] - mx); s += e[i]; }
  float inv = 1.f / s;
#pragma unroll
  for (int i = 0; i < 20; ++i) p[i] = e[i] * inv;
}

__global__ __launch_bounds__(256) void k_sample(
    const bf16_t* __restrict__ value,   // [B, LQ, H*HD] bf16
    const bf16_t* __restrict__ off,     // [B*LQ, 320] bf16
    const float* __restrict__ attn,     // [B*LQ, 160] f32 (post-softmax)
    const float* __restrict__ rp,       // [B*LQ, 5, 2] f32
    bf16_t* __restrict__ core)          // [B*LQ, 256] bf16
{
  const int Wl[5] = {100, 50, 25, 13, 7};
  const int st[5] = {0, 10000, 12500, 13125, 13294};
  int bq = blockIdx.x;
  int t = threadIdx.x;
  int h = t >> 5, d = t & 31;
  __shared__ float s_off[320];
  __shared__ float s_attn[160];
  __shared__ float s_rp[10];
  {
    const bf16_t* op = off + (size_t)bq * 320;
    for (int i = t; i < 320; i += 256) s_off[i] = (float)op[i];
    const float* ap = attn + (size_t)bq * 160;
    if (t < 160) s_attn[t] = ap[t];
    if (t < 10) s_rp[t] = rp[(size_t)bq * 10 + t];
  }
  __syncthreads();
  int b = bq / LQ_;
  const bf16_t* vb = value + (size_t)b * LQ_ * 256 + h * 32 + d;
  float acc = 0.f;
#pragma unroll
  for (int lvl = 0; lvl < 5; ++lvl) {
    float W = (float)Wl[lvl];
    float rx = s_rp[lvl * 2], ry = s_rp[lvl * 2 + 1];
#pragma unroll
    for (int p = 0; p < 4; ++p) {
      int base = (h * 5 + lvl) * 4 + p;
      float px = rx * W + s_off[base * 2]     - 0.5f;  // loc_x*W - 0.5
      float py = ry * W + s_off[base * 2 + 1] - 0.5f;
      float aw = s_attn[base];
      float x0f = floorf(px), y0f = floorf(py);
      float wx1 = px - x0f, wy1 = py - y0f;
      int x0 = (int)x0f, y0 = (int)y0f;
      float smp = 0.f;
#pragma unroll
      for (int dy = 0; dy < 2; ++dy) {
        int yi = y0 + dy;
        bool vy = (yi >= 0) & (yi < Wl[lvl]);
        int yc = min(max(yi, 0), Wl[lvl] - 1);
        float wy = dy ? wy1 : 1.f - wy1;
#pragma unroll
        for (int dx = 0; dx < 2; ++dx) {
          int xi = x0 + dx;
          bool vx = (xi >= 0) & (xi < Wl[lvl]);
          int xc = min(max(xi, 0), Wl[lvl] - 1);
          float w = wy * (dx ? wx1 : 1.f - wx1);
          float v = (float)vb[(size_t)(st[lvl] + yc * Wl[lvl] + xc) * 256];
          smp += (vx & vy) ? w * v : 0.f;
        }
      }
      acc += aw * smp;
    }
  }
  core[(size_t)bq * 256 + t] = (bf16_t)acc;
}

// out = LN(a + res [+ eb]) * g + beta   (a f32, res templated, out templated)
template <typename TR, typename TO>
__global__ __launch_bounds__(256) void k_ln(
    const float* __restrict__ a, const TR* __restrict__ res,
    const float* __restrict__ eb, const float* __restrict__ g,
    const float* __restrict__ beta, TO* __restrict__ out)
{
  int row = blockIdx.x, t = threadIdx.x;
  size_t i = (size_t)row * 256 + t;
  float v = a[i] + (float)res[i];
  if (eb) v += eb[t];
  float s1 = v, s2 = v * v;
#pragma unroll
  for (int o = 32; o > 0; o >>= 1) { s1 += __shfl_down(s1, o); s2 += __shfl_down(s2, o); }
  __shared__ float r1[4], r2[4];
  int wv = t >> 6, lane = t & 63;
  if (lane == 0) { r1[wv] = s1; r2[wv] = s2; }
  __syncthreads();
  float S1 = r1[0] + r1[1] + r1[2] + r1[3];
  float S2 = r2[0] + r2[1] + r2[2] + r2[3];
  float m = S1 * (1.f / 256.f);
  float var = S2 * (1.f / 256.f) - m * m;
  float inv = rsqrtf(var + 1e-5f);
  out[i] = (TO)(((v - m) * inv) * g[t] + beta[t]);
}

// ---------------- launcher ----------------
// ws regions (lifetimes):
//   W  2.62MB : transposed bf16 weights (whole run)
//   B  27.3MB : qb (addpos..attnGEMM) -> coreb (sample..outGEMM) -> hidden (FFN)
//   C  34.2MB : attnb f32 (attnGEMM..sample) -> attn_out bf16 (outGEMM..ln1)
//   E  54.7MB : valb bf16 (valGEMM..sample) -> xbuf f32 (ln1..end)
//   d_out     : offb bf16 [M,320] (offGEMM..sample) -> ffn_acc f32 [M,256] -> final out (in-place)
// peak ws ~ 119 MB
extern "C" void kernel_launch(void* const* d_in, const int* in_sizes, int n_in,
                              void* d_out, int out_size, void* d_ws, size_t ws_size,
                              hipStream_t stream) {
  const float* src   = (const float*)d_in[0];
  const float* pos   = (const float*)d_in[1];
  const float* rp    = (const float*)d_in[2];
  const float* W_off = (const float*)d_in[5];
  const float* b_off = (const float*)d_in[6];
  const float* W_attn= (const float*)d_in[7];
  const float* b_attn= (const float*)d_in[8];
  const float* W_val = (const float*)d_in[9];
  const float* b_val = (const float*)d_in[10];
  const float* W_out = (const float*)d_in[11];
  const float* b_out = (const float*)d_in[12];
  const float* g1    = (const float*)d_in[13];
  const float* beta1 = (const float*)d_in[14];
  const float* W1    = (const float*)d_in[15];
  const float* bl1   = (const float*)d_in[16];
  const float* W2    = (const float*)d_in[17];
  const float* bl2   = (const float*)d_in[18];
  const float* g2    = (const float*)d_in[19];
  const float* beta2 = (const float*)d_in[20];

  char* ws = (char*)d_ws;
  size_t o = 0;
  bf16_t* wToff  = (bf16_t*)(ws + o); o += 320 * 256 * 2;
  bf16_t* wTattn = (bf16_t*)(ws + o); o += 160 * 256 * 2;
  bf16_t* wTval  = (bf16_t*)(ws + o); o += 256 * 256 * 2;
  bf16_t* wTout  = (bf16_t*)(ws + o); o += 256 * 256 * 2;
  bf16_t* wT1    = (bf16_t*)(ws + o); o += 2048 * 256 * 2;
  bf16_t* wT2    = (bf16_t*)(ws + o); o += 2048 * 256 * 2;
  o = (o + 255) & ~(size_t)255;
  char* Breg = ws + o; o += (size_t)M_ * 256 * 2;   // 27.3MB
  char* Creg = ws + o; o += (size_t)M_ * 160 * 4;   // 34.2MB
  char* Ereg = ws + o; o += (size_t)M_ * 256 * 4;   // 54.7MB

  bf16_t* qb      = (bf16_t*)Breg;
  bf16_t* coreb   = (bf16_t*)Breg;
  bf16_t* hidden  = (bf16_t*)Breg;
  float*  attnb   = (float*) Creg;
  bf16_t* attn_out= (bf16_t*)Creg;
  bf16_t* valb    = (bf16_t*)Ereg;
  float*  xbuf    = (float*) Ereg;
  bf16_t* offb    = (bf16_t*)d_out;   // [M,320] bf16 = 34.2MB <= 54.7MB
  float*  ffn_acc = (float*) d_out;   // [M,256] f32 (after offb dead)
  float*  outf    = (float*) d_out;

  auto tg = [](int n) { return dim3((n + 255) / 256); };
  k_transpose<<<tg(256 * 320), 256, 0, stream>>>(W_off, wToff, 256, 320);
  k_transpose<<<tg(256 * 160), 256, 0, stream>>>(W_attn, wTattn, 256, 160);
  k_transpose<<<tg(256 * 256), 256, 0, stream>>>(W_val, wTval, 256, 256);
  k_transpose<<<tg(256 * 256), 256, 0, stream>>>(W_out, wTout, 256, 256);
  k_transpose<<<tg(256 * 2048), 256, 0, stream>>>(W1, wT1, 256, 2048);
  k_transpose<<<tg(2048 * 256), 256, 0, stream>>>(W2, wT2, 2048, 256);

  int n8 = M_ * D_ / 8;
  k_addpos<<<(n8 + 255) / 256, 256, 0, stream>>>(src, pos, qb, n8);

  dim3 blk(256);
  int gM = (M_ + BM - 1) / BM;   // 417
  // offsets: [M,320] bf16 (into d_out scratch)
  gemm_bt<MODE_BF16, false><<<dim3(gM, 3), blk, 0, stream>>>(qb, 256, wToff, 256, b_off, offb, 320, M_, 320, 256);
  // attn logits: [M,160] f32
  gemm_bt<MODE_F32, false><<<dim3(gM, 2), blk, 0, stream>>>(qb, 256, wTattn, 256, b_attn, attnb, 160, M_, 160, 256);
  k_softmax20<<<tg(M_ * H_), 256, 0, stream>>>(attnb, M_ * H_);
  // value: [M,256] bf16, A = src (f32)
  gemm_bt<MODE_BF16, true><<<dim3(gM, 2), blk, 0, stream>>>(src, 256, wTval, 256, b_val, valb, 256, M_, 256, 256);
  k_sample<<<M_, 256, 0, stream>>>(valb, offb, attnb, rp, coreb);
  // out-projection: [M,256] bf16 (attnb dead)
  gemm_bt<MODE_BF16, false><<<dim3(gM, 2), blk, 0, stream>>>(coreb, 256, wTout, 256, b_out, attn_out, 256, M_, 256, 256);
  // x = LN(src + attn_out) -> f32 xbuf (valb dead)
  k_ln<bf16_t, float><<<M_, 256, 0, stream>>>(src, attn_out, (const float*)nullptr, g1, beta1, xbuf);
  // FFN in 8 chunks of 256 hidden cols; accumulate f32 into d_out (offb dead)
  for (int c = 0; c < 8; ++c) {
    gemm_bt<MODE_BF16_RELU, true><<<dim3(gM, 2), blk, 0, stream>>>(
        xbuf, 256, wT1 + (size_t)c * 256 * 256, 256, bl1 + c * 256, hidden, 256, M_, 256, 256);
    if (c == 0)
      gemm_bt<MODE_F32, false><<<dim3(gM, 2), blk, 0, stream>>>(
          hidden, 256, wT2 + c * 256, 2048, (const float*)nullptr, ffn_acc, 256, M_, 256, 256);
    else
      gemm_bt<MODE_F32_ACC, false><<<dim3(gM, 2), blk, 0, stream>>>(
          hidden, 256, wT2 + c * 256, 2048, (const float*)nullptr, ffn_acc, 256, M_, 256, 256);
  }
  // final LN in-place on d_out (per-thread read-before-write, barrier-separated)
  k_ln<float, float><<<M_, 256, 0, stream>>>(xbuf, ffn_acc, bl2, g2, beta2, outf);
}

// Round 5
// 1049.672 us; speedup vs baseline: 1.5078x; 1.5078x over previous
//
#include <hip/hip_runtime.h>
#include <hip/hip_bf16.h>

typedef __bf16 bf16_t;
typedef __bf16 bf16x8 __attribute__((ext_vector_type(8)));
typedef float f32x4 __attribute__((ext_vector_type(4)));

#define B_    4
#define LQ_   13343
#define D_    256
#define H_    8
#define HD_   32
#define DFF_  2048
#define M_    (B_ * LQ_)   // 53372 tokens

// ---------------- GEMM: C = A[M,K] @ Bt[N,K]^T + bias ----------------
#define BM 128
#define BN 128
#define BK 32
#define LDSS 40   // 80 B stride (5x16B): b128-safe, breaks bank aliasing

#define MODE_F32       0
#define MODE_F32_ACC   1
#define MODE_BF16      2
#define MODE_BF16_RELU 3

template <int MODE, bool AF32>
__global__ __launch_bounds__(256) void gemm_bt(
    const void* __restrict__ Av, int lda,
    const bf16_t* __restrict__ Bt, int ldb,
    const float* __restrict__ bias,
    void* __restrict__ Cv, int ldc,
    int M, int N, int K)
{
  __shared__ alignas(16) bf16_t As[BM * LDSS];
  __shared__ alignas(16) bf16_t Bs[BN * LDSS];
  const int tid  = threadIdx.x;
  const int wave = tid >> 6, lane = tid & 63;
  const int m0 = blockIdx.x * BM;
  const int n0 = blockIdx.y * BN;
  const int wm = (wave & 1) * 64;
  const int wn = (wave >> 1) * 64;
  const int lrow = lane & 15;
  const int quad = lane >> 4;

  f32x4 acc[4][4] = {};

  const int r0 = tid >> 2;          // 0..63
  const int kc = (tid & 3) * 8;     // 0,8,16,24

  for (int kt = 0; kt < K; kt += BK) {
    bf16x8 a0 = {}, a1 = {}, b0 = {}, b1 = {};
    int gm0 = m0 + r0, gm1 = m0 + r0 + 64;
    if (AF32) {
      const float* Af = (const float*)Av;
      if (gm0 < M) {
        const float* p = Af + (size_t)gm0 * lda + kt + kc;
#pragma unroll
        for (int j = 0; j < 8; ++j) a0[j] = (bf16_t)p[j];
      }
      if (gm1 < M) {
        const float* p = Af + (size_t)gm1 * lda + kt + kc;
#pragma unroll
        for (int j = 0; j < 8; ++j) a1[j] = (bf16_t)p[j];
      }
    } else {
      const bf16_t* Ab = (const bf16_t*)Av;
      if (gm0 < M) a0 = *(const bf16x8*)(Ab + (size_t)gm0 * lda + kt + kc);
      if (gm1 < M) a1 = *(const bf16x8*)(Ab + (size_t)gm1 * lda + kt + kc);
    }
    int gn0 = n0 + r0, gn1 = n0 + r0 + 64;
    if (gn0 < N) b0 = *(const bf16x8*)(Bt + (size_t)gn0 * ldb + kt + kc);
    if (gn1 < N) b1 = *(const bf16x8*)(Bt + (size_t)gn1 * ldb + kt + kc);
    __syncthreads();
    *(bf16x8*)(&As[r0 * LDSS + kc])        = a0;
    *(bf16x8*)(&As[(r0 + 64) * LDSS + kc]) = a1;
    *(bf16x8*)(&Bs[r0 * LDSS + kc])        = b0;
    *(bf16x8*)(&Bs[(r0 + 64) * LDSS + kc]) = b1;
    __syncthreads();
    bf16x8 af[4], bfr[4];
#pragma unroll
    for (int i = 0; i < 4; ++i)
      af[i] = *(const bf16x8*)(&As[(wm + i * 16 + lrow) * LDSS + quad * 8]);
#pragma unroll
    for (int j = 0; j < 4; ++j)
      bfr[j] = *(const bf16x8*)(&Bs[(wn + j * 16 + lrow) * LDSS + quad * 8]);
#pragma unroll
    for (int i = 0; i < 4; ++i)
#pragma unroll
      for (int j = 0; j < 4; ++j)
        acc[i][j] = __builtin_amdgcn_mfma_f32_16x16x32_bf16(af[i], bfr[j], acc[i][j], 0, 0, 0);
  }

  float*  Cf = (float*)Cv;
  bf16_t* Cb = (bf16_t*)Cv;
#pragma unroll
  for (int i = 0; i < 4; ++i) {
#pragma unroll
    for (int j = 0; j < 4; ++j) {
      int gn = n0 + wn + j * 16 + lrow;
      if (gn >= N) continue;
      float bv = bias ? bias[gn] : 0.f;
#pragma unroll
      for (int r = 0; r < 4; ++r) {
        int gm = m0 + wm + i * 16 + quad * 4 + r;
        if (gm >= M) continue;
        float v = acc[i][j][r] + bv;
        size_t ci = (size_t)gm * ldc + gn;
        if (MODE == MODE_F32)          Cf[ci] = v;
        else if (MODE == MODE_F32_ACC) Cf[ci] += v;
        else if (MODE == MODE_BF16)    Cb[ci] = (bf16_t)v;
        else                           Cb[ci] = (bf16_t)(v > 0.f ? v : 0.f);
      }
    }
  }
}

// ---------------- small kernels ----------------
__global__ void k_transpose(const float* __restrict__ in, bf16_t* __restrict__ out,
                            int K, int N) {
  int idx = blockIdx.x * 256 + threadIdx.x;
  if (idx >= K * N) return;
  int n = idx / K, k = idx - n * K;
  out[idx] = (bf16_t)in[(size_t)k * N + n];
}

__global__ void k_addpos(const float* __restrict__ a, const float* __restrict__ b,
                         bf16_t* __restrict__ o, int n8) {
  int i = blockIdx.x * blockDim.x + threadIdx.x;
  if (i >= n8) return;
  bf16x8 z;
#pragma unroll
  for (int j = 0; j < 8; ++j) z[j] = (bf16_t)(a[i * 8 + j] + b[i * 8 + j]);
  ((bf16x8*)o)[i] = z;
}

__global__ void k_softmax20(float* __restrict__ a, int rows) {
  int r = blockIdx.x * blockDim.x + threadIdx.x;
  if (r >= rows) return;
  float* p = a + (size_t)r * 20;
  float mx = p[0];
#pragma unroll
  for (int i = 1; i < 20; ++i) mx = fmaxf(mx, p[i]);
  float e[20], s = 0.f;
#pragma unroll
  for (int i = 0; i < 20; ++i) { e[i] = expf(p[i] - mx); s += e[i]; }
  float inv = 1.f / s;
#pragma unroll
  for (int i = 0; i < 20; ++i) p[i] = e[i] * inv;
}

// 8 queries/block; 32 threads/query: h = (s>>2), d-group = (s&3)*8, bf16x8 loads.
__global__ __launch_bounds__(256) void k_sample(
    const bf16_t* __restrict__ value,   // [B*LQ, 256]
    const bf16_t* __restrict__ off,     // [M, 320]
    const float* __restrict__ attn,     // [M, 160] post-softmax
    const float* __restrict__ rp,       // [M, 10]
    bf16_t* __restrict__ core)          // [M, 256]
{
  const int Wl[5] = {100, 50, 25, 13, 7};
  const int st[5] = {0, 10000, 12500, 13125, 13294};
  __shared__ alignas(16) bf16_t s_off[8][320];
  __shared__ alignas(16) float  s_attn[8][160];
  __shared__ float s_rp[8][10];
  const int t = threadIdx.x;
  const int bq0 = blockIdx.x * 8;
  for (int i = t; i < 320; i += 256) {
    int q = i / 40, e = i - q * 40;
    if (bq0 + q < M_) {
      *(bf16x8*)&s_off[q][e * 8] = *(const bf16x8*)(off + (size_t)(bq0 + q) * 320 + e * 8);
      *(f32x4*)&s_attn[q][e * 4] = *(const f32x4*)(attn + (size_t)(bq0 + q) * 160 + e * 4);
    }
  }
  if (t < 80) {
    int q = t / 10, e = t - q * 10;
    if (bq0 + q < M_) s_rp[q][e] = rp[(size_t)(bq0 + q) * 10 + e];
  }
  __syncthreads();

  const int wq = t >> 5, s = t & 31;
  const int h = s >> 2, d0 = (s & 3) * 8;
  const int bq = bq0 + wq;
  if (bq >= M_) return;
  const int b = bq / LQ_;
  const bf16_t* vbase = value + ((size_t)b * LQ_) * 256 + h * 32 + d0;
  float acc[8] = {};
#pragma unroll
  for (int lvl = 0; lvl < 5; ++lvl) {
    const float W = (float)Wl[lvl];
    const float rx = s_rp[wq][lvl * 2], ry = s_rp[wq][lvl * 2 + 1];
#pragma unroll
    for (int p = 0; p < 4; ++p) {
      const int base = (h * 5 + lvl) * 4 + p;
      float px = rx * W + (float)s_off[wq][base * 2]     - 0.5f;
      float py = ry * W + (float)s_off[wq][base * 2 + 1] - 0.5f;
      float aw = s_attn[wq][base];
      float x0f = floorf(px), y0f = floorf(py);
      float wx1 = px - x0f, wy1 = py - y0f;
      int x0 = (int)x0f, y0 = (int)y0f;
#pragma unroll
      for (int dy = 0; dy < 2; ++dy) {
        int yi = y0 + dy;
        bool vy = (yi >= 0) & (yi < Wl[lvl]);
        int yc = min(max(yi, 0), Wl[lvl] - 1);
        float wy = dy ? wy1 : 1.f - wy1;
#pragma unroll
        for (int dx = 0; dx < 2; ++dx) {
          int xi = x0 + dx;
          bool vx = (xi >= 0) & (xi < Wl[lvl]);
          int xc = min(max(xi, 0), Wl[lvl] - 1);
          float cw = (vx & vy) ? aw * wy * (dx ? wx1 : 1.f - wx1) : 0.f;
          bf16x8 v = *(const bf16x8*)(vbase + (size_t)(st[lvl] + yc * Wl[lvl] + xc) * 256);
#pragma unroll
          for (int j = 0; j < 8; ++j) acc[j] += cw * (float)v[j];
        }
      }
    }
  }
  bf16x8 o;
#pragma unroll
  for (int j = 0; j < 8; ++j) o[j] = (bf16_t)acc[j];
  *(bf16x8*)(core + (size_t)bq * 256 + h * 32 + d0) = o;
}

// out = LN(a + res [+ eb]) * g + beta
template <typename TA, typename TR, typename TO>
__global__ __launch_bounds__(256) void k_ln(
    const TA* __restrict__ a, const TR* __restrict__ res,
    const float* __restrict__ eb, const float* __restrict__ g,
    const float* __restrict__ beta, TO* __restrict__ out)
{
  int row = blockIdx.x, t = threadIdx.x;
  size_t i = (size_t)row * 256 + t;
  float v = (float)a[i] + (float)res[i];
  if (eb) v += eb[t];
  float s1 = v, s2 = v * v;
#pragma unroll
  for (int o = 32; o > 0; o >>= 1) { s1 += __shfl_down(s1, o); s2 += __shfl_down(s2, o); }
  __shared__ float r1[4], r2[4];
  int wv = t >> 6, lane = t & 63;
  if (lane == 0) { r1[wv] = s1; r2[wv] = s2; }
  __syncthreads();
  float S1 = r1[0] + r1[1] + r1[2] + r1[3];
  float S2 = r2[0] + r2[1] + r2[2] + r2[3];
  float m = S1 * (1.f / 256.f);
  float var = S2 * (1.f / 256.f) - m * m;
  float inv = rsqrtf(var + 1e-5f);
  out[i] = (TO)(((v - m) * inv) * g[t] + beta[t]);
}

// ---------------- launcher ----------------
// ws regions (lifetimes, all sizes exact):
//   W 2.62MB  : transposed bf16 weights (whole run)
//   Areg 27.33: qb (addpos..attnGEMM) -> coreb (sample..outGEMM) -> hidden[minimal tier]
//   Creg 34.16: attnb f32 (attnGEMM..sample) -> attn_out bf16 [M,256]=27.33 (outGEMM..ln1)
//   Dreg 27.33: valb (valGEMM..sample) -> xbuf bf16 [M,256]=27.33 (ln1..ln2)
//   [tier] hidden [M,cw] bf16 beyond Dreg only if ws_size permits
//   d_out     : offb bf16 [M,320]=34.16 (offGEMM..sample) -> ffn f32 acc [M,256]=54.65 -> final
// minimal-tier ws total = 91.4MB (proven in R3)
extern "C" void kernel_launch(void* const* d_in, const int* in_sizes, int n_in,
                              void* d_out, int out_size, void* d_ws, size_t ws_size,
                              hipStream_t stream) {
  const float* src   = (const float*)d_in[0];
  const float* pos   = (const float*)d_in[1];
  const float* rp    = (const float*)d_in[2];
  const float* W_off = (const float*)d_in[5];
  const float* b_off = (const float*)d_in[6];
  const float* W_attn= (const float*)d_in[7];
  const float* b_attn= (const float*)d_in[8];
  const float* W_val = (const float*)d_in[9];
  const float* b_val = (const float*)d_in[10];
  const float* W_out = (const float*)d_in[11];
  const float* b_out = (const float*)d_in[12];
  const float* g1    = (const float*)d_in[13];
  const float* beta1 = (const float*)d_in[14];
  const float* W1    = (const float*)d_in[15];
  const float* bl1   = (const float*)d_in[16];
  const float* W2    = (const float*)d_in[17];
  const float* bl2   = (const float*)d_in[18];
  const float* g2    = (const float*)d_in[19];
  const float* beta2 = (const float*)d_in[20];

  char* ws = (char*)d_ws;
  const size_t SZ_TOK = (size_t)M_ * 256 * 2;  // 27,326,464
  const size_t SZ_ATT = (size_t)M_ * 160 * 4;  // 34,158,080

  size_t o = 0;
  bf16_t* wToff  = (bf16_t*)(ws + o); o += 320 * 256 * 2;
  bf16_t* wTattn = (bf16_t*)(ws + o); o += 160 * 256 * 2;
  bf16_t* wTval  = (bf16_t*)(ws + o); o += 256 * 256 * 2;
  bf16_t* wTout  = (bf16_t*)(ws + o); o += 256 * 256 * 2;
  bf16_t* wT1    = (bf16_t*)(ws + o); o += 2048 * 256 * 2;
  bf16_t* wT2    = (bf16_t*)(ws + o); o += 2048 * 256 * 2;
  o = (o + 255) & ~(size_t)255;
  char* Areg = ws + o; o += SZ_TOK;   // qb -> coreb -> hidden (minimal)
  char* Creg = ws + o; o += SZ_ATT;   // attnb -> attn_out
  char* Dreg = ws + o; o += SZ_TOK;   // valb -> xbuf
  size_t base = o;                    // ~91.4MB

  // tier: hidden chunk width (ws_size constant across calls -> identical work/launch)
  int cw; char* Hreg;
  if (ws_size >= base + (size_t)M_ * 2048 * 2)      { cw = 2048; Hreg = ws + base; }
  else if (ws_size >= base + (size_t)M_ * 512 * 2)  { cw = 512;  Hreg = ws + base; }
  else                                              { cw = 256;  Hreg = Areg; }

  bf16_t* qb      = (bf16_t*)Areg;
  bf16_t* coreb   = (bf16_t*)Areg;
  float*  attnb   = (float*) Creg;
  bf16_t* attn_out= (bf16_t*)Creg;    // 27.33MB <= 34.16MB region
  bf16_t* valb    = (bf16_t*)Dreg;
  bf16_t* xbuf    = (bf16_t*)Dreg;    // after valb dead (post-sample)
  bf16_t* hidden  = (bf16_t*)Hreg;
  bf16_t* offb    = (bf16_t*)d_out;   // 34.16MB <= 54.65MB, dead before FFN acc
  float*  outf    = (float*) d_out;

  auto tg = [](int n) { return dim3((n + 255) / 256); };
  k_transpose<<<tg(256 * 320), 256, 0, stream>>>(W_off, wToff, 256, 320);
  k_transpose<<<tg(256 * 160), 256, 0, stream>>>(W_attn, wTattn, 256, 160);
  k_transpose<<<tg(256 * 256), 256, 0, stream>>>(W_val, wTval, 256, 256);
  k_transpose<<<tg(256 * 256), 256, 0, stream>>>(W_out, wTout, 256, 256);
  k_transpose<<<tg(256 * 2048), 256, 0, stream>>>(W1, wT1, 256, 2048);
  k_transpose<<<tg(2048 * 256), 256, 0, stream>>>(W2, wT2, 2048, 256);

  int n8 = M_ * D_ / 8;
  k_addpos<<<(n8 + 255) / 256, 256, 0, stream>>>(src, pos, qb, n8);

  dim3 blk(256);
  int gM = (M_ + BM - 1) / BM;   // 417
  gemm_bt<MODE_BF16, false><<<dim3(gM, 3), blk, 0, stream>>>(qb, 256, wToff, 256, b_off, offb, 320, M_, 320, 256);
  gemm_bt<MODE_F32, false><<<dim3(gM, 2), blk, 0, stream>>>(qb, 256, wTattn, 256, b_attn, attnb, 160, M_, 160, 256);
  k_softmax20<<<tg(M_ * H_), 256, 0, stream>>>(attnb, M_ * H_);
  gemm_bt<MODE_BF16, true><<<dim3(gM, 2), blk, 0, stream>>>(src, 256, wTval, 256, b_val, valb, 256, M_, 256, 256);
  k_sample<<<dim3((M_ + 7) / 8), blk, 0, stream>>>(valb, offb, attnb, rp, coreb);
  gemm_bt<MODE_BF16, false><<<dim3(gM, 2), blk, 0, stream>>>(coreb, 256, wTout, 256, b_out, attn_out, 256, M_, 256, 256);
  // ln1: xbuf (Dreg) <- LN(src + attn_out); valb dead, coreb dead after this GEMM
  k_ln<float, bf16_t, bf16_t><<<M_, 256, 0, stream>>>(src, attn_out, (const float*)nullptr, g1, beta1, xbuf);

  int nchunks = DFF_ / cw;
  for (int c = 0; c < nchunks; ++c) {
    gemm_bt<MODE_BF16_RELU, false><<<dim3(gM, cw / BN), blk, 0, stream>>>(
        xbuf, 256, wT1 + (size_t)c * cw * 256, 256, bl1 + c * cw, hidden, cw, M_, cw, 256);
    if (c == 0)
      gemm_bt<MODE_F32, false><<<dim3(gM, 2), blk, 0, stream>>>(
          hidden, cw, wT2 + c * cw, 2048, (const float*)nullptr, outf, 256, M_, 256, cw);
    else
      gemm_bt<MODE_F32_ACC, false><<<dim3(gM, 2), blk, 0, stream>>>(
          hidden, cw, wT2 + c * cw, 2048, (const float*)nullptr, outf, 256, M_, 256, cw);
  }
  // final LN in-place on d_out (per-thread read-before-write)
  k_ln<bf16_t, float, float><<<M_, 256, 0, stream>>>(xbuf, outf, bl2, g2, beta2, outf);
}